// Round 1
// baseline (260.809 us; speedup 1.0000x reference)
//
#include <hip/hip_runtime.h>

// Problem constants (from reference): B=1, L=2048, DIM=16, HEADS=1, DIM_HEAD=1.
// Key insight: softmax over the size-1 heads axis == 1.0, so attention is
// all-ones and q,k are dead. Output[0,i,j,d] = v[i]*W_out[d,0] + b_out[d],
// independent of j, where v[i] = x[i,:] . W_qkv[2,:].
// => compute a 2048x16 row table, then broadcast-fill 256 MiB of output.

#define L_SEQ 2048
#define DIM 16

// Kernel 1: r[i][d] = (x[i,:] . W_qkv[2,:]) * W_out[d] + b_out[d]
__global__ void compute_rows(const float* __restrict__ x,
                             const float* __restrict__ W_qkv,
                             const float* __restrict__ W_out,
                             const float* __restrict__ b_out,
                             float* __restrict__ r) {
    int i = blockIdx.x * blockDim.x + threadIdx.x;
    if (i >= L_SEQ) return;
    const float* wv = W_qkv + 2 * DIM;  // third row of W_qkv (the v projection)
    float v = 0.f;
#pragma unroll
    for (int d = 0; d < DIM; ++d) v += x[i * DIM + d] * wv[d];
#pragma unroll
    for (int d = 0; d < DIM; ++d) r[i * DIM + d] = v * W_out[d] + b_out[d];
}

// Kernel 2: out[((i*L)+j)*16 + d] = r[i][d] for all j.
// One block per row i. Row span = L*DIM floats = 8192 float4 = 128 KiB.
// Thread t writes float4 positions t, t+256, ... ; since 256 % 4 == 0,
// its d-group (t & 3) is loop-invariant -> one register float4, 32 stores.
__global__ void __launch_bounds__(256) fill_rows(const float* __restrict__ r,
                                                 float4* __restrict__ out) {
    const int i = blockIdx.x;
    const int t = threadIdx.x;
    const int dg = t & 3;
    const float4* r4 = (const float4*)(r + (size_t)i * DIM);
    const float4 val = r4[dg];
    float4* row_out = out + (size_t)i * (L_SEQ * DIM / 4);
#pragma unroll
    for (int k = 0; k < (L_SEQ * DIM / 4) / 256; ++k) {  // 32 iterations
        row_out[t + k * 256] = val;
    }
}

extern "C" void kernel_launch(void* const* d_in, const int* in_sizes, int n_in,
                              void* d_out, int out_size, void* d_ws, size_t ws_size,
                              hipStream_t stream) {
    const float* x     = (const float*)d_in[0];  // (1, 2048, 16)
    const float* W_qkv = (const float*)d_in[1];  // (3, 16)
    const float* W_out = (const float*)d_in[2];  // (16, 1)
    const float* b_out = (const float*)d_in[3];  // (16,)
    float* r = (float*)d_ws;                     // 2048*16 floats = 128 KiB scratch

    compute_rows<<<(L_SEQ + 255) / 256, 256, 0, stream>>>(x, W_qkv, W_out, b_out, r);
    fill_rows<<<L_SEQ, 256, 0, stream>>>(r, (float4*)d_out);
}